// Round 2
// baseline (499.313 us; speedup 1.0000x reference)
//
#include <hip/hip_runtime.h>

#define BATCH   1024
#define IDIM    256
#define ODIM    256
#define GRIDSZ  300
#define KS_     64             // K-splits over i
#define IPW     4              // i per block = IDIM/KS_
#define CHUNKS  19             // g-chunks of 16 pairs per i (last chunk: 4 pad slots)
#define INV2PI  0.15915494309189535f

typedef __attribute__((ext_vector_type(8))) short  short8;
typedef __attribute__((ext_vector_type(4))) float  f32x4;
typedef __attribute__((ext_vector_type(4))) unsigned int u32x4;

// bf16 pair pack: round-half-up + v_perm byte select (3 VALU ops). PROVEN (R5/fkan2).
// low16 = bf16(c), high16 = bf16(s).
__device__ __forceinline__ unsigned pk(float c, float s) {
  unsigned a = __float_as_uint(c) + 0x8000u;
  unsigned b = __float_as_uint(s) + 0x8000u;
  return __builtin_amdgcn_perm(b, a, 0x07060302u);
}

// (c,s) *= (C,S)  — Givens rotation, 2 mul + 2 fma
__device__ __forceinline__ void rot(float& c, float& s, float C, float S) {
  float t1 = s * S, t2 = c * S;
  float cn = __builtin_fmaf(c, C, -t1);
  s = __builtin_fmaf(s, C, t2);
  c = cn;
}

// cos/sin of 2*pi*rev via v_fract + v_cos (revolutions; exact range reduction)
__device__ __forceinline__ void cossin(float rev, float& c, float& s) {
  c = __builtin_amdgcn_cosf(__builtin_amdgcn_fractf(rev));
  s = __builtin_amdgcn_cosf(__builtin_amdgcn_fractf(rev - 0.25f));
}

__global__ void init_out(const float* __restrict__ bias, float* __restrict__ out) {
  const int idx = blockIdx.x * 256 + threadIdx.x;
  out[idx] = bias[idx & (ODIM - 1)];
}

// Fused FourierKAN (R5-verbatim structure, harness-proven): reads fc fp32
// directly, packs A and B to bf16 pairs in-register via perm-pk, no LDS, no
// barriers, no preprocessing pass. A generated by rotation recurrence
// (seeded per i-row, advanced delta-g=16 per chunk). B double-buffered in
// registers. Pad (g=300..303) handled by shifting fq==3's last-chunk load
// in-bounds and zeroing the matching A-state.
__global__ __launch_bounds__(256, 3) void fkan_main(
    const float* __restrict__ x, const float* __restrict__ fc,
    float* __restrict__ out) {
  const int tid = threadIdx.x, id = blockIdx.x;
  // XCD swizzle: the 4 m-siblings of one (n,ks) are consecutive on XCD id&7,
  // so their shared fc slice (614 KB) stays in that XCD's L2.
  const int z = id & 7;
  const int m = (id >> 3) & 3;           // M/256
  const int nk = (id >> 5) * 8 + z;      // 0..255
  const int n  = nk & 3;                 // N/64
  const int ks = nk >> 2;                // 0..63
  const int wave = tid >> 6, lane = tid & 63;
  const int fr = lane & 15, fq = lane >> 4;
  const int mbase = m * 256 + wave * 64;   // 4 waves stacked along M
  const int nbase = n * 64;

  f32x4 acc[4][4];
#pragma unroll
  for (int a_ = 0; a_ < 4; ++a_)
#pragma unroll
    for (int b_ = 0; b_ < 4; ++b_)
      acc[a_][b_] = (f32x4){0.f, 0.f, 0.f, 0.f};

  float r1c[4], r1s[4], r16c[4], r16s[4], sc_[4], ss_[4];
  f32x4 B0[4], B1[4];
  unsigned bF[4][4];
  int voff[4];
  const float* b1base = fc + (size_t)ODIM * IDIM * GRIDSZ;

#pragma unroll 1
  for (int il = 0; il < IPW; ++il) {
    const int i = ks * IPW + il;
#pragma unroll
    for (int tI = 0; tI < 4; ++tI) {
      float xr = x[(size_t)(mbase + tI * 16 + fr) * IDIM + i] * INV2PI;
      cossin(xr, r1c[tI], r1s[tI]);                   // delta-k = 1
      cossin(16.0f * xr, r16c[tI], r16s[tI]);         // delta-g = 16 per chunk
      cossin((float)(fq * 4 + 1) * xr, sc_[tI], ss_[tI]);
    }
#pragma unroll
    for (int tJ = 0; tJ < 4; ++tJ) {
      voff[tJ] = ((nbase + tJ * 16 + fr) * IDIM + i) * GRIDSZ + fq * 4;
      B0[tJ] = *(const f32x4*)(fc + voff[tJ]);
      B1[tJ] = *(const f32x4*)(b1base + voff[tJ]);
    }
#pragma unroll 1
    for (int chunk = 0; chunk < CHUNKS; ++chunk) {
      // pack current B (consumes in-flight loads)
#pragma unroll
      for (int tJ = 0; tJ < 4; ++tJ) {
        bF[tJ][0] = pk(B0[tJ].x, B1[tJ].x);
        bF[tJ][1] = pk(B0[tJ].y, B1[tJ].y);
        bF[tJ][2] = pk(B0[tJ].z, B1[tJ].z);
        bF[tJ][3] = pk(B0[tJ].w, B1[tJ].w);
      }
      // prefetch next chunk; fq==3 at last chunk would read g=300..303 (OOB):
      // shift back 4 elements — matching A-state is zeroed below, so inert.
      if (chunk < CHUNKS - 1) {
        const int sub = ((chunk == CHUNKS - 2) & (fq == 3)) ? 4 : 0;
#pragma unroll
        for (int tJ = 0; tJ < 4; ++tJ) {
          voff[tJ] += 16;
          const int vu = voff[tJ] - sub;
          B0[tJ] = *(const f32x4*)(fc + vu);
          B1[tJ] = *(const f32x4*)(b1base + vu);
        }
      }
      if (chunk == CHUNKS - 1) {
        if (fq == 3) {
#pragma unroll
          for (int tI = 0; tI < 4; ++tI) { sc_[tI] = 0.0f; ss_[tI] = 0.0f; }
        }
      }
      // A frags on the fly + MFMA
#pragma unroll
      for (int tI = 0; tI < 4; ++tI) {
        float c = sc_[tI], s = ss_[tI];
        unsigned a0 = pk(c, s);
        rot(c, s, r1c[tI], r1s[tI]); unsigned a1 = pk(c, s);
        rot(c, s, r1c[tI], r1s[tI]); unsigned a2 = pk(c, s);
        rot(c, s, r1c[tI], r1s[tI]); unsigned a3 = pk(c, s);
        rot(sc_[tI], ss_[tI], r16c[tI], r16s[tI]);   // advance state by delta-g=16
        short8 aV = __builtin_bit_cast(short8, (u32x4){a0, a1, a2, a3});
#pragma unroll
        for (int tJ = 0; tJ < 4; ++tJ) {
          short8 bV = __builtin_bit_cast(short8,
              (u32x4){bF[tJ][0], bF[tJ][1], bF[tJ][2], bF[tJ][3]});
          acc[tI][tJ] = __builtin_amdgcn_mfma_f32_16x16x32_bf16(aV, bV, acc[tI][tJ], 0, 0, 0);
        }
      }
    }
  }

  // epilogue: C/D layout col=lane&15, row=(lane>>4)*4+reg [m89]; K-split fp32 atomics
  const int ob = mbase + fq * 4;
  const int oj = nbase + fr;
#pragma unroll
  for (int tI = 0; tI < 4; ++tI)
#pragma unroll
    for (int tJ = 0; tJ < 4; ++tJ) {
      float* dst = out + (size_t)(ob + tI * 16) * ODIM + (oj + tJ * 16);
#pragma unroll
      for (int rr = 0; rr < 4; ++rr)
        unsafeAtomicAdd(dst + rr * ODIM, acc[tI][tJ][rr]);
    }
}

extern "C" void kernel_launch(void* const* d_in, const int* in_sizes, int n_in,
                              void* d_out, int out_size, void* d_ws, size_t ws_size,
                              hipStream_t stream) {
  const float* x    = (const float*)d_in[0];
  const float* fc   = (const float*)d_in[1];
  const float* bias = (const float*)d_in[2];
  float* out = (float*)d_out;

  init_out<<<dim3(BATCH * ODIM / 256), dim3(256), 0, stream>>>(bias, out);
  fkan_main<<<dim3(4 * 4 * KS_), dim3(256), 0, stream>>>(x, fc, out);
}

// Round 3
// 478.229 us; speedup vs baseline: 1.0441x; 1.0441x over previous
//
#include <hip/hip_runtime.h>

#define BATCH   1024
#define IDIM    256
#define ODIM    256
#define GRIDSZ  300
#define KS_     64             // K-splits over i
#define IPW     4              // i per block = IDIM/KS_
#define CHUNKS  19             // g-chunks of 16 pairs per i (last chunk: 4 pad slots)
#define NSTEPS  (IPW * CHUNKS) // 76
#define INV2PI  0.15915494309189535f

typedef __attribute__((ext_vector_type(8))) short  short8;
typedef __attribute__((ext_vector_type(4))) float  f32x4;
typedef __attribute__((ext_vector_type(4))) unsigned int u32x4;

// bf16 pair pack: round-half-up + v_perm byte select (3 VALU ops). PROVEN.
// low16 = bf16(c), high16 = bf16(s).
__device__ __forceinline__ unsigned pk(float c, float s) {
  unsigned a = __float_as_uint(c) + 0x8000u;
  unsigned b = __float_as_uint(s) + 0x8000u;
  return __builtin_amdgcn_perm(b, a, 0x07060302u);
}

// (c,s) *= (C,S)  — Givens rotation, 2 mul + 2 fma
__device__ __forceinline__ void rot(float& c, float& s, float C, float S) {
  float t1 = s * S, t2 = c * S;
  float cn = __builtin_fmaf(c, C, -t1);
  s = __builtin_fmaf(s, C, t2);
  c = cn;
}

// cos/sin of 2*pi*rev via v_fract + v_cos (revolutions; exact range reduction)
__device__ __forceinline__ void cossin(float rev, float& c, float& s) {
  c = __builtin_amdgcn_cosf(__builtin_amdgcn_fractf(rev));
  s = __builtin_amdgcn_cosf(__builtin_amdgcn_fractf(rev - 0.25f));
}

__global__ void init_out(const float* __restrict__ bias, float* __restrict__ out) {
  const int idx = blockIdx.x * 256 + threadIdx.x;
  out[idx] = bias[idx & (ODIM - 1)];
}

// fkan2 (proven 146 us) with conversion fused into the staging phase:
// staging loads the two fp32 fc planes directly and packs to bf16 pairs
// inline (perm-pk) before the ds_write_b128. Everything else verbatim:
// 4KB-per-buffer LDS double-buffer shared by 4 waves, one barrier/chunk,
// loads issued right after the barrier, ds_write after the MFMA body.
// Pad (g=300..303): fq==3 staging threads shift the last-chunk load
// in-bounds and write ZEROS to LDS (reproduces W's zero pad).
__global__ __launch_bounds__(256, 4) void fkan_fused(
    const float* __restrict__ x, const float* __restrict__ fc,
    float* __restrict__ out) {
  __shared__ alignas(16) unsigned int Blds[2][1024];   // 8 KB total

  const int tid = threadIdx.x, id = blockIdx.x;
  // XCD swizzle: the 4 m-siblings of one (n,ks) are consecutive on XCD id&7.
  const int z = id & 7;
  const int m = (id >> 3) & 3;           // M/256
  const int nk = (id >> 5) * 8 + z;      // 0..255
  const int n  = nk & 3;                 // N/64
  const int ks = nk >> 2;                // 0..63

  const int wave = tid >> 6, lane = tid & 63;
  const int fr = lane & 15, fq = lane >> 4;
  const int mbase = m * 256 + wave * 64;   // 4 waves stacked along M
  const int nbase = n * 64;

  f32x4 acc[4][4];
#pragma unroll
  for (int a_ = 0; a_ < 4; ++a_)
#pragma unroll
    for (int b_ = 0; b_ < 4; ++b_)
      acc[a_][b_] = (f32x4){0.f, 0.f, 0.f, 0.f};

  float r1c[4], r1s[4], r16c[4], r16s[4], sc_[4], ss_[4];

  const float* b1 = fc + (size_t)ODIM * IDIM * GRIDSZ;   // sin-coef plane

  // staging thread's fc offset for the current chunk:
  // row = nbase + wave*16 + fr (j), i = ks*IPW + il, g = gs*16 + fq*4
  int fo = ((nbase + wave * 16 + fr) * IDIM + ks * IPW) * GRIDSZ + fq * 4;
  const int sa = wave * 256 + lane * 4;    // this wave's staging slot (dwords)

  // prologue: stage chunk 0 into buffer 0 (gs=0, no pad case)
  f32x4 La = *(const f32x4*)(fc + fo);
  f32x4 Lb = *(const f32x4*)(b1 + fo);
  *(u32x4*)&Blds[0][sa] =
      (u32x4){pk(La.x, Lb.x), pk(La.y, Lb.y), pk(La.z, Lb.z), pk(La.w, Lb.w)};

  int gs = 0, il = 0;

#pragma unroll 2
  for (int S = 0; S < NSTEPS; ++S) {
    __syncthreads();   // buf[S&1] fully staged by all waves; no loads in flight

    // issue next chunk's loads (consumed before the next barrier)
    bool zpad = false;
    if (S < NSTEPS - 1) {
      int cg = gs + 1;
      if (cg == CHUNKS) { cg = 0; fo += GRIDSZ - (CHUNKS - 1) * 16; }  // +12
      else fo += 16;
      zpad = (cg == CHUNKS - 1) & (fq == 3);   // next chunk's pad quads
      const int sub = zpad ? 4 : 0;            // shift in-bounds; zeroed at write
      La = *(const f32x4*)(fc + fo - sub);
      Lb = *(const f32x4*)(b1 + fo - sub);
    }

    // seed A recurrence at i-boundaries (S = 0,19,38,57; block-uniform branch)
    if (gs == 0) {
      const int i = ks * IPW + il;
#pragma unroll
      for (int tI = 0; tI < 4; ++tI) {
        const float xr = x[(size_t)(mbase + tI * 16 + fr) * IDIM + i] * INV2PI;
        cossin(xr, r1c[tI], r1s[tI]);                   // delta-k = 1
        cossin(16.0f * xr, r16c[tI], r16s[tI]);         // delta-g = 16 per chunk
        cossin((float)(fq * 4 + 1) * xr, sc_[tI], ss_[tI]);
      }
    }

    // B fragments for this chunk (all 4 waves read all 4 frags; ~4-way b128)
    const unsigned int* buf = &Blds[S & 1][0];
    short8 bV0 = __builtin_bit_cast(short8, *(const u32x4*)(buf + lane * 4));
    short8 bV1 = __builtin_bit_cast(short8, *(const u32x4*)(buf + 256 + lane * 4));
    short8 bV2 = __builtin_bit_cast(short8, *(const u32x4*)(buf + 512 + lane * 4));
    short8 bV3 = __builtin_bit_cast(short8, *(const u32x4*)(buf + 768 + lane * 4));

    // A frags on the fly + MFMA (pad k-slots hit zeroed B dwords)
#pragma unroll
    for (int tI = 0; tI < 4; ++tI) {
      float c = sc_[tI], s = ss_[tI];
      unsigned a0 = pk(c, s);
      rot(c, s, r1c[tI], r1s[tI]); unsigned a1 = pk(c, s);
      rot(c, s, r1c[tI], r1s[tI]); unsigned a2 = pk(c, s);
      rot(c, s, r1c[tI], r1s[tI]); unsigned a3 = pk(c, s);
      rot(sc_[tI], ss_[tI], r16c[tI], r16s[tI]);   // advance state by delta-g=16
      short8 aV = __builtin_bit_cast(short8, (u32x4){a0, a1, a2, a3});
      acc[tI][0] = __builtin_amdgcn_mfma_f32_16x16x32_bf16(aV, bV0, acc[tI][0], 0, 0, 0);
      acc[tI][1] = __builtin_amdgcn_mfma_f32_16x16x32_bf16(aV, bV1, acc[tI][1], 0, 0, 0);
      acc[tI][2] = __builtin_amdgcn_mfma_f32_16x16x32_bf16(aV, bV2, acc[tI][2], 0, 0, 0);
      acc[tI][3] = __builtin_amdgcn_mfma_f32_16x16x32_bf16(aV, bV3, acc[tI][3], 0, 0, 0);
    }

    // pack + stage next chunk into the alternate buffer
    if (S < NSTEPS - 1) {
      u32x4 w = (u32x4){pk(La.x, Lb.x), pk(La.y, Lb.y),
                        pk(La.z, Lb.z), pk(La.w, Lb.w)};
      if (zpad) w = (u32x4){0u, 0u, 0u, 0u};
      *(u32x4*)&Blds[(S + 1) & 1][sa] = w;
    }

    gs++; if (gs == CHUNKS) { gs = 0; ++il; }
  }

  // epilogue: C/D layout col=lane&15, row=(lane>>4)*4+reg [m89]; K-split fp32 atomics
  const int ob = mbase + fq * 4;
  const int oj = nbase + fr;
#pragma unroll
  for (int tI = 0; tI < 4; ++tI)
#pragma unroll
    for (int tJ = 0; tJ < 4; ++tJ) {
      float* dst = out + (size_t)(ob + tI * 16) * ODIM + (oj + tJ * 16);
#pragma unroll
      for (int rr = 0; rr < 4; ++rr)
        unsafeAtomicAdd(dst + rr * ODIM, acc[tI][tJ][rr]);
    }
}

extern "C" void kernel_launch(void* const* d_in, const int* in_sizes, int n_in,
                              void* d_out, int out_size, void* d_ws, size_t ws_size,
                              hipStream_t stream) {
  const float* x    = (const float*)d_in[0];
  const float* fc   = (const float*)d_in[1];
  const float* bias = (const float*)d_in[2];
  float* out = (float*)d_out;

  init_out<<<dim3(BATCH * ODIM / 256), dim3(256), 0, stream>>>(bias, out);
  fkan_fused<<<dim3(4 * 4 * KS_), dim3(256), 0, stream>>>(x, fc, out);
}

// Round 4
// 380.205 us; speedup vs baseline: 1.3133x; 1.2578x over previous
//
#include <hip/hip_runtime.h>

#define BATCH   1024
#define IDIM    256
#define ODIM    256
#define GRIDSZ  300
#define KS_     64             // K-splits over i
#define IPW     4              // i per block = IDIM/KS_
#define CHUNKS  19             // g-chunks of 16 pairs per i (last chunk: 4 pad slots)
#define NSTEPS  (IPW * CHUNKS) // 76
#define INV2PI  0.15915494309189535f

typedef __attribute__((ext_vector_type(8))) short  short8;
typedef __attribute__((ext_vector_type(4))) float  f32x4;
typedef __attribute__((ext_vector_type(4))) unsigned int u32x4;

// bf16 pair pack: round-half-up + v_perm byte select (3 VALU ops). PROVEN.
// low16 = bf16(c), high16 = bf16(s).
__device__ __forceinline__ unsigned pk(float c, float s) {
  unsigned a = __float_as_uint(c) + 0x8000u;
  unsigned b = __float_as_uint(s) + 0x8000u;
  return __builtin_amdgcn_perm(b, a, 0x07060302u);
}

// (c,s) *= (C,S)  — Givens rotation, 2 mul + 2 fma
__device__ __forceinline__ void rot(float& c, float& s, float C, float S) {
  float t1 = s * S, t2 = c * S;
  float cn = __builtin_fmaf(c, C, -t1);
  s = __builtin_fmaf(s, C, t2);
  c = cn;
}

// cos/sin of 2*pi*rev via v_fract + v_cos (revolutions; exact range reduction)
__device__ __forceinline__ void cossin(float rev, float& c, float& s) {
  c = __builtin_amdgcn_cosf(__builtin_amdgcn_fractf(rev));
  s = __builtin_amdgcn_cosf(__builtin_amdgcn_fractf(rev - 0.25f));
}

__global__ void init_out(const float* __restrict__ bias, float* __restrict__ out) {
  const int idx = blockIdx.x * 256 + threadIdx.x;
  out[idx] = bias[idx & (ODIM - 1)];
}

// Fused fkan2: conversion folded into the LDS staging phase (loads the two
// fp32 fc planes, packs to bf16 pairs inline before ds_write_b128).
// launch_bounds (256,3): R3's (256,4) capped the unified reg file at 128
// (64 AGPR acc + 64 VGPR) and the extra La/Lb liveness spilled -> 520 MB of
// scratch HBM writes (rocprof: WRITE_SIZE 593 MB vs 75 MB, MfmaUtil 10%).
// 3 blocks/CU gives a 168-reg budget; est. need ~144 -> no spill.
// Pad (g=300..303): fq==3 staging threads shift the last-chunk load
// in-bounds and write ZEROS to LDS (reproduces the zero pad).
__global__ __launch_bounds__(256, 3) void fkan_fused(
    const float* __restrict__ x, const float* __restrict__ fc,
    float* __restrict__ out) {
  __shared__ alignas(16) unsigned int Blds[2][1024];   // 8 KB total

  const int tid = threadIdx.x, id = blockIdx.x;
  // XCD swizzle: the 4 m-siblings of one (n,ks) are consecutive on XCD id&7.
  const int z = id & 7;
  const int m = (id >> 3) & 3;           // M/256
  const int nk = (id >> 5) * 8 + z;      // 0..255
  const int n  = nk & 3;                 // N/64
  const int ks = nk >> 2;                // 0..63

  const int wave = tid >> 6, lane = tid & 63;
  const int fr = lane & 15, fq = lane >> 4;
  const int mbase = m * 256 + wave * 64;   // 4 waves stacked along M
  const int nbase = n * 64;

  f32x4 acc[4][4];
#pragma unroll
  for (int a_ = 0; a_ < 4; ++a_)
#pragma unroll
    for (int b_ = 0; b_ < 4; ++b_)
      acc[a_][b_] = (f32x4){0.f, 0.f, 0.f, 0.f};

  float r1c[4], r1s[4], r16c[4], r16s[4], sc_[4], ss_[4];

  const float* b1 = fc + (size_t)ODIM * IDIM * GRIDSZ;   // sin-coef plane

  // staging thread's fc offset for the current chunk:
  // row = nbase + wave*16 + fr (j), i = ks*IPW + il, g = gs*16 + fq*4
  int fo = ((nbase + wave * 16 + fr) * IDIM + ks * IPW) * GRIDSZ + fq * 4;
  const int sa = wave * 256 + lane * 4;    // this wave's staging slot (dwords)

  // prologue: stage chunk 0 into buffer 0 (gs=0, no pad case)
  f32x4 La = *(const f32x4*)(fc + fo);
  f32x4 Lb = *(const f32x4*)(b1 + fo);
  *(u32x4*)&Blds[0][sa] =
      (u32x4){pk(La.x, Lb.x), pk(La.y, Lb.y), pk(La.z, Lb.z), pk(La.w, Lb.w)};

  int gs = 0, il = 0;

#pragma unroll 2
  for (int S = 0; S < NSTEPS; ++S) {
    __syncthreads();   // buf[S&1] fully staged by all waves; no loads in flight

    // issue next chunk's loads (consumed before the next barrier)
    bool zpad = false;
    if (S < NSTEPS - 1) {
      int cg = gs + 1;
      if (cg == CHUNKS) { cg = 0; fo += GRIDSZ - (CHUNKS - 1) * 16; }  // +12
      else fo += 16;
      zpad = (cg == CHUNKS - 1) & (fq == 3);   // next chunk's pad quads
      const int sub = zpad ? 4 : 0;            // shift in-bounds; zeroed at write
      La = *(const f32x4*)(fc + fo - sub);
      Lb = *(const f32x4*)(b1 + fo - sub);
    }

    // seed A recurrence at i-boundaries (S = 0,19,38,57; block-uniform branch)
    if (gs == 0) {
      const int i = ks * IPW + il;
#pragma unroll
      for (int tI = 0; tI < 4; ++tI) {
        const float xr = x[(size_t)(mbase + tI * 16 + fr) * IDIM + i] * INV2PI;
        cossin(xr, r1c[tI], r1s[tI]);                   // delta-k = 1
        cossin(16.0f * xr, r16c[tI], r16s[tI]);         // delta-g = 16 per chunk
        cossin((float)(fq * 4 + 1) * xr, sc_[tI], ss_[tI]);
      }
    }

    // B fragments for this chunk (all 4 waves read all 4 frags; ~4-way b128)
    const unsigned int* buf = &Blds[S & 1][0];
    short8 bV0 = __builtin_bit_cast(short8, *(const u32x4*)(buf + lane * 4));
    short8 bV1 = __builtin_bit_cast(short8, *(const u32x4*)(buf + 256 + lane * 4));
    short8 bV2 = __builtin_bit_cast(short8, *(const u32x4*)(buf + 512 + lane * 4));
    short8 bV3 = __builtin_bit_cast(short8, *(const u32x4*)(buf + 768 + lane * 4));

    // A frags on the fly + MFMA (pad k-slots hit zeroed B dwords)
#pragma unroll
    for (int tI = 0; tI < 4; ++tI) {
      float c = sc_[tI], s = ss_[tI];
      unsigned a0 = pk(c, s);
      rot(c, s, r1c[tI], r1s[tI]); unsigned a1 = pk(c, s);
      rot(c, s, r1c[tI], r1s[tI]); unsigned a2 = pk(c, s);
      rot(c, s, r1c[tI], r1s[tI]); unsigned a3 = pk(c, s);
      rot(sc_[tI], ss_[tI], r16c[tI], r16s[tI]);   // advance state by delta-g=16
      short8 aV = __builtin_bit_cast(short8, (u32x4){a0, a1, a2, a3});
      acc[tI][0] = __builtin_amdgcn_mfma_f32_16x16x32_bf16(aV, bV0, acc[tI][0], 0, 0, 0);
      acc[tI][1] = __builtin_amdgcn_mfma_f32_16x16x32_bf16(aV, bV1, acc[tI][1], 0, 0, 0);
      acc[tI][2] = __builtin_amdgcn_mfma_f32_16x16x32_bf16(aV, bV2, acc[tI][2], 0, 0, 0);
      acc[tI][3] = __builtin_amdgcn_mfma_f32_16x16x32_bf16(aV, bV3, acc[tI][3], 0, 0, 0);
    }

    // pack + stage next chunk into the alternate buffer
    if (S < NSTEPS - 1) {
      u32x4 w = (u32x4){pk(La.x, Lb.x), pk(La.y, Lb.y),
                        pk(La.z, Lb.z), pk(La.w, Lb.w)};
      if (zpad) w = (u32x4){0u, 0u, 0u, 0u};
      *(u32x4*)&Blds[(S + 1) & 1][sa] = w;
    }

    gs++; if (gs == CHUNKS) { gs = 0; ++il; }
  }

  // epilogue: C/D layout col=lane&15, row=(lane>>4)*4+reg [m89]; K-split fp32 atomics
  const int ob = mbase + fq * 4;
  const int oj = nbase + fr;
#pragma unroll
  for (int tI = 0; tI < 4; ++tI)
#pragma unroll
    for (int tJ = 0; tJ < 4; ++tJ) {
      float* dst = out + (size_t)(ob + tI * 16) * ODIM + (oj + tJ * 16);
#pragma unroll
      for (int rr = 0; rr < 4; ++rr)
        unsafeAtomicAdd(dst + rr * ODIM, acc[tI][tJ][rr]);
    }
}

extern "C" void kernel_launch(void* const* d_in, const int* in_sizes, int n_in,
                              void* d_out, int out_size, void* d_ws, size_t ws_size,
                              hipStream_t stream) {
  const float* x    = (const float*)d_in[0];
  const float* fc   = (const float*)d_in[1];
  const float* bias = (const float*)d_in[2];
  float* out = (float*)d_out;

  init_out<<<dim3(BATCH * ODIM / 256), dim3(256), 0, stream>>>(bias, out);
  fkan_fused<<<dim3(4 * 4 * KS_), dim3(256), 0, stream>>>(x, fc, out);
}

// Round 5
// 326.485 us; speedup vs baseline: 1.5294x; 1.1645x over previous
//
#include <hip/hip_runtime.h>

#define BATCH   1024
#define IDIM    256
#define ODIM    256
#define GRIDSZ  300
#define KS_     64             // K-splits over i
#define IPW     4              // i per block = IDIM/KS_
#define CHUNKS  19             // g-chunks of 16 pairs per i (last chunk: 4 pad slots)
#define NSTEPS  (IPW * CHUNKS) // 76
#define INV2PI  0.15915494309189535f

typedef __attribute__((ext_vector_type(8))) short  short8;
typedef __attribute__((ext_vector_type(4))) float  f32x4;
typedef __attribute__((ext_vector_type(4))) unsigned int u32x4;

// bf16 pair pack: round-half-up + v_perm byte select (3 VALU ops). PROVEN.
// low16 = bf16(c), high16 = bf16(s).
__device__ __forceinline__ unsigned pk(float c, float s) {
  unsigned a = __float_as_uint(c) + 0x8000u;
  unsigned b = __float_as_uint(s) + 0x8000u;
  return __builtin_amdgcn_perm(b, a, 0x07060302u);
}

// async global->LDS DMA, 16B per lane. LDS dest must be wave-uniform base +
// lane*16 (our staging layout is exactly lane-linear per wave). [m97/m03]
__device__ __forceinline__ void dma16(const float* g, const float* l) {
  __builtin_amdgcn_global_load_lds(
      (const __attribute__((address_space(1))) unsigned int*)(g),
      (__attribute__((address_space(3))) unsigned int*)(l), 16, 0, 0);
}

// (c,s) *= (C,S)  — Givens rotation, 2 mul + 2 fma
__device__ __forceinline__ void rot(float& c, float& s, float C, float S) {
  float t1 = s * S, t2 = c * S;
  float cn = __builtin_fmaf(c, C, -t1);
  s = __builtin_fmaf(s, C, t2);
  c = cn;
}

// cos/sin of 2*pi*rev via v_fract + v_cos (revolutions; exact range reduction)
__device__ __forceinline__ void cossin(float rev, float& c, float& s) {
  c = __builtin_amdgcn_cosf(__builtin_amdgcn_fractf(rev));
  s = __builtin_amdgcn_cosf(__builtin_amdgcn_fractf(rev - 0.25f));
}

__global__ void init_out(const float* __restrict__ bias, float* __restrict__ out) {
  const int idx = blockIdx.x * 256 + threadIdx.x;
  out[idx] = bias[idx & (ODIM - 1)];
}

// Fused fkan with zero-VGPR staging: the two fp32 fc planes are DMA'd to an
// 8 KB LDS buffer via global_load_lds (no register round-trip), and packed
// to bf16 pairs on the LDS->LDS path (vmcnt(0) + 2x ds_read_b128 + 4 pk +
// ds_write_b128) at the END of the MFMA body, so DMA latency hides under
// compute. This removes the 8 La/Lb registers that pushed R4 to 132 regs
// (> the 128 cap for 4 blocks/CU) and forced a 2-round tail at (256,3).
// fp32 buffer needs no barrier: each thread packs exactly the bytes its own
// wave staged (same-wave vmcnt ordering); WAR across iterations is cut by
// the loop-top __syncthreads. Packed dbuf + barrier discipline = R4 verbatim.
// Pad (g=300..303): fq==3 last-chunk DMA shifts 16B in-bounds; pack writes
// zeros for those slots.
__global__ __launch_bounds__(256, 4) void fkan_dma(
    const float* __restrict__ x, const float* __restrict__ fc,
    float* __restrict__ out) {
  __shared__ alignas(16) unsigned int Bp[2][1024];   // packed bf16-pair dbuf, 8 KB
  __shared__ alignas(16) float Bf[2048];             // fp32 DMA landing, 8 KB

  const int tid = threadIdx.x, id = blockIdx.x;
  // XCD swizzle: the 4 m-siblings of one (n,ks) are consecutive on XCD id&7.
  const int z = id & 7;
  const int m = (id >> 3) & 3;           // M/256
  const int nk = (id >> 5) * 8 + z;      // 0..255
  const int n  = nk & 3;                 // N/64
  const int ks = nk >> 2;                // 0..63

  const int wave = tid >> 6, lane = tid & 63;
  const int fr = lane & 15, fq = lane >> 4;
  const int mbase = m * 256 + wave * 64;   // 4 waves stacked along M
  const int nbase = n * 64;

  f32x4 acc[4][4];
#pragma unroll
  for (int a_ = 0; a_ < 4; ++a_)
#pragma unroll
    for (int b_ = 0; b_ < 4; ++b_)
      acc[a_][b_] = (f32x4){0.f, 0.f, 0.f, 0.f};

  float r1c[4], r1s[4], r16c[4], r16s[4], sc_[4], ss_[4];

  const float* b1 = fc + (size_t)ODIM * IDIM * GRIDSZ;   // sin-coef plane

  // staging thread's fc offset for the current chunk:
  // row = nbase + wave*16 + fr (j), i = ks*IPW + il, g = gs*16 + fq*4
  int fo = ((nbase + wave * 16 + fr) * IDIM + ks * IPW) * GRIDSZ + fq * 4;
  const int sa = wave * 256 + lane * 4;     // packed slot (dwords), lane-linear
  const float* myBf0 = &Bf[sa];             // own fp32 plane-0 quad
  const float* myBf1 = &Bf[1024 + sa];      // own fp32 plane-1 quad

  // prologue: DMA chunk 0, wait (wave-local), pack into Bp[0]
  dma16(fc + fo, myBf0);
  dma16(b1 + fo, myBf1);
  asm volatile("s_waitcnt vmcnt(0)" ::: "memory");
  {
    const f32x4 La = *(const f32x4*)myBf0;
    const f32x4 Lb = *(const f32x4*)myBf1;
    *(u32x4*)&Bp[0][sa] =
        (u32x4){pk(La.x, Lb.x), pk(La.y, Lb.y), pk(La.z, Lb.z), pk(La.w, Lb.w)};
  }

  int gs = 0, il = 0;

#pragma unroll 2
  for (int S = 0; S < NSTEPS; ++S) {
    __syncthreads();   // Bp[S&1] staged by all waves; Bf reads of iter S-1 drained

    // issue next chunk's DMA (lands during the MFMA body below)
    bool zpad = false;
    if (S < NSTEPS - 1) {
      int cg = gs + 1;
      if (cg == CHUNKS) { cg = 0; fo += GRIDSZ - (CHUNKS - 1) * 16; }  // +12
      else fo += 16;
      zpad = (cg == CHUNKS - 1) & (fq == 3);   // next chunk's pad quads
      const int sub = zpad ? 4 : 0;            // shift in-bounds; zeroed at pack
      dma16(fc + fo - sub, myBf0);
      dma16(b1 + fo - sub, myBf1);
    }

    // seed A recurrence at i-boundaries (S = 0,19,38,57; block-uniform branch)
    if (gs == 0) {
      const int i = ks * IPW + il;
#pragma unroll
      for (int tI = 0; tI < 4; ++tI) {
        const float xr = x[(size_t)(mbase + tI * 16 + fr) * IDIM + i] * INV2PI;
        cossin(xr, r1c[tI], r1s[tI]);                   // delta-k = 1
        cossin(16.0f * xr, r16c[tI], r16s[tI]);         // delta-g = 16 per chunk
        cossin((float)(fq * 4 + 1) * xr, sc_[tI], ss_[tI]);
      }
    }

    // B fragments for this chunk (all 4 waves read all 4 frags)
    const unsigned int* buf = &Bp[S & 1][0];
    short8 bV0 = __builtin_bit_cast(short8, *(const u32x4*)(buf + lane * 4));
    short8 bV1 = __builtin_bit_cast(short8, *(const u32x4*)(buf + 256 + lane * 4));
    short8 bV2 = __builtin_bit_cast(short8, *(const u32x4*)(buf + 512 + lane * 4));
    short8 bV3 = __builtin_bit_cast(short8, *(const u32x4*)(buf + 768 + lane * 4));

    // A frags on the fly + MFMA (pad k-slots hit zeroed B dwords)
#pragma unroll
    for (int tI = 0; tI < 4; ++tI) {
      float c = sc_[tI], s = ss_[tI];
      unsigned a0 = pk(c, s);
      rot(c, s, r1c[tI], r1s[tI]); unsigned a1 = pk(c, s);
      rot(c, s, r1c[tI], r1s[tI]); unsigned a2 = pk(c, s);
      rot(c, s, r1c[tI], r1s[tI]); unsigned a3 = pk(c, s);
      rot(sc_[tI], ss_[tI], r16c[tI], r16s[tI]);   // advance state by delta-g=16
      short8 aV = __builtin_bit_cast(short8, (u32x4){a0, a1, a2, a3});
      acc[tI][0] = __builtin_amdgcn_mfma_f32_16x16x32_bf16(aV, bV0, acc[tI][0], 0, 0, 0);
      acc[tI][1] = __builtin_amdgcn_mfma_f32_16x16x32_bf16(aV, bV1, acc[tI][1], 0, 0, 0);
      acc[tI][2] = __builtin_amdgcn_mfma_f32_16x16x32_bf16(aV, bV2, acc[tI][2], 0, 0, 0);
      acc[tI][3] = __builtin_amdgcn_mfma_f32_16x16x32_bf16(aV, bV3, acc[tI][3], 0, 0, 0);
    }

    // pack next chunk LDS->LDS: wave-local vmcnt, own bytes only
    if (S < NSTEPS - 1) {
      asm volatile("s_waitcnt vmcnt(0)" ::: "memory");
      const f32x4 La = *(const f32x4*)myBf0;
      const f32x4 Lb = *(const f32x4*)myBf1;
      u32x4 w = (u32x4){pk(La.x, Lb.x), pk(La.y, Lb.y),
                        pk(La.z, Lb.z), pk(La.w, Lb.w)};
      if (zpad) w = (u32x4){0u, 0u, 0u, 0u};
      *(u32x4*)&Bp[(S + 1) & 1][sa] = w;
    }

    gs++; if (gs == CHUNKS) { gs = 0; ++il; }
  }

  // epilogue: C/D layout col=lane&15, row=(lane>>4)*4+reg [m89]; K-split fp32 atomics
  const int ob = mbase + fq * 4;
  const int oj = nbase + fr;
#pragma unroll
  for (int tI = 0; tI < 4; ++tI)
#pragma unroll
    for (int tJ = 0; tJ < 4; ++tJ) {
      float* dst = out + (size_t)(ob + tI * 16) * ODIM + (oj + tJ * 16);
#pragma unroll
      for (int rr = 0; rr < 4; ++rr)
        unsafeAtomicAdd(dst + rr * ODIM, acc[tI][tJ][rr]);
    }
}

extern "C" void kernel_launch(void* const* d_in, const int* in_sizes, int n_in,
                              void* d_out, int out_size, void* d_ws, size_t ws_size,
                              hipStream_t stream) {
  const float* x    = (const float*)d_in[0];
  const float* fc   = (const float*)d_in[1];
  const float* bias = (const float*)d_in[2];
  float* out = (float*)d_out;

  init_out<<<dim3(BATCH * ODIM / 256), dim3(256), 0, stream>>>(bias, out);
  fkan_dma<<<dim3(4 * 4 * KS_), dim3(256), 0, stream>>>(x, fc, out);
}

// Round 6
// 322.189 us; speedup vs baseline: 1.5498x; 1.0133x over previous
//
#include <hip/hip_runtime.h>

#define BATCH   1024
#define IDIM    256
#define ODIM    256
#define GRIDSZ  300
#define KS_     64             // K-splits over i
#define IPW     4              // i per block = IDIM/KS_
#define CHUNKS  19             // g-chunks of 16 pairs per i (last chunk: 4 pad slots)
#define NSTEPS  (IPW * CHUNKS) // 76
#define INV2PI  0.15915494309189535f

typedef __attribute__((ext_vector_type(8))) short  short8;
typedef __attribute__((ext_vector_type(4))) float  f32x4;
typedef __attribute__((ext_vector_type(4))) unsigned int u32x4;

// bf16 pair pack: round-half-up + v_perm byte select (3 VALU ops). PROVEN.
// low16 = bf16(c), high16 = bf16(s).
__device__ __forceinline__ unsigned pk(float c, float s) {
  unsigned a = __float_as_uint(c) + 0x8000u;
  unsigned b = __float_as_uint(s) + 0x8000u;
  return __builtin_amdgcn_perm(b, a, 0x07060302u);
}

// async global->LDS DMA, 16B per lane (lane-linear dest). [m97/m03, R5-proven]
__device__ __forceinline__ void dma16(const float* g, const float* l) {
  __builtin_amdgcn_global_load_lds(
      (const __attribute__((address_space(1))) unsigned int*)(g),
      (__attribute__((address_space(3))) unsigned int*)(l), 16, 0, 0);
}

// (c,s) *= (C,S)  — Givens rotation, 2 mul + 2 fma
__device__ __forceinline__ void rot(float& c, float& s, float C, float S) {
  float t1 = s * S, t2 = c * S;
  float cn = __builtin_fmaf(c, C, -t1);
  s = __builtin_fmaf(s, C, t2);
  c = cn;
}

// cos/sin of 2*pi*rev via v_fract + v_cos (revolutions; exact range reduction)
__device__ __forceinline__ void cossin(float rev, float& c, float& s) {
  c = __builtin_amdgcn_cosf(__builtin_amdgcn_fractf(rev));
  s = __builtin_amdgcn_cosf(__builtin_amdgcn_fractf(rev - 0.25f));
}

__global__ void init_out(const float* __restrict__ bias, float* __restrict__ out) {
  const int idx = blockIdx.x * 256 + threadIdx.x;
  out[idx] = bias[idx & (ODIM - 1)];
}

// R5 + 2-deep DMA pipeline with counted vmcnt (T3/T4 mechanism):
//   iter S: raw s_barrier (lgkmcnt(0) only, NO vmcnt drain) -> Bp[S&1] visible
//           seed (if i-boundary), issue DMA for chunk S+2 into Bf[S&1],
//           MFMA body on Bp[S&1],
//           pack chunk S+1: s_waitcnt vmcnt(2) (chunk S+2's DMAs stay in
//           flight ACROSS the next barrier), Bf[(S+1)&1] -> Bp[(S+1)&1].
// DMA in-flight time goes from ~300 cyc (R5: issue->vmcnt(0) same iter) to
// ~1.5 iterations -> HBM latency fully hidden. Bf regions are wave-private
// (no cross-wave hazard); Bp WAR across the single barrier is safe since
// each wave's bV reads are consumed by its MFMAs before it arrives.
// sched_barrier(0) fences pin compiler motion around the asm barrier [rule 18].
// Pad (g=300..303): fq==3 DMA for a gd==18 chunk shifts 16B in-bounds (flag
// carried one iter, applied as a zero-write at pack -> Bp zero pad).
__global__ __launch_bounds__(256, 4) void fkan_pipe(
    const float* __restrict__ x, const float* __restrict__ fc,
    float* __restrict__ out) {
  __shared__ alignas(16) unsigned int Bp[2][1024];   // packed bf16-pair dbuf, 8 KB
  __shared__ alignas(16) float Bf[2][2048];          // fp32 DMA landing, 16 KB

  const int tid = threadIdx.x, id = blockIdx.x;
  // XCD swizzle: the 4 m-siblings of one (n,ks) are consecutive on XCD id&7.
  const int z = id & 7;
  const int m = (id >> 3) & 3;           // M/256
  const int nk = (id >> 5) * 8 + z;      // 0..255
  const int n  = nk & 3;                 // N/64
  const int ks = nk >> 2;                // 0..63

  const int wave = tid >> 6, lane = tid & 63;
  const int fr = lane & 15, fq = lane >> 4;
  const int mbase = m * 256 + wave * 64;   // 4 waves stacked along M
  const int nbase = n * 64;

  f32x4 acc[4][4];
#pragma unroll
  for (int a_ = 0; a_ < 4; ++a_)
#pragma unroll
    for (int b_ = 0; b_ < 4; ++b_)
      acc[a_][b_] = (f32x4){0.f, 0.f, 0.f, 0.f};

  float r1c[4], r1s[4], r16c[4], r16s[4], sc_[4], ss_[4];

  const float* b1 = fc + (size_t)ODIM * IDIM * GRIDSZ;   // sin-coef plane

  // staging thread's fc offset: row j = nbase+wave*16+fr, i = ks*IPW+il,
  // g = gchunk*16 + fq*4
  int fo = ((nbase + wave * 16 + fr) * IDIM + ks * IPW) * GRIDSZ + fq * 4;
  const int sa = wave * 256 + lane * 4;     // lane-linear slot (dwords)

  // prologue: DMA chunks 0 (parity 0) and 1 (parity 1)
  dma16(fc + fo, &Bf[0][sa]);
  dma16(b1 + fo, &Bf[0][1024 + sa]);
  fo += 16;                                 // chunk 1 (no wrap, no pad)
  dma16(fc + fo, &Bf[1][sa]);
  dma16(b1 + fo, &Bf[1][1024 + sa]);

  // pack chunk 0 -> Bp[0]; chunk 1's 2 DMAs stay in flight
  asm volatile("s_waitcnt vmcnt(2)" ::: "memory");
  {
    const f32x4 La = *(const f32x4*)&Bf[0][sa];
    const f32x4 Lb = *(const f32x4*)&Bf[0][1024 + sa];
    *(u32x4*)&Bp[0][sa] =
        (u32x4){pk(La.x, Lb.x), pk(La.y, Lb.y), pk(La.z, Lb.z), pk(La.w, Lb.w)};
  }

  int gs = 0, il = 0;      // compute-chunk counters (chunk S)
  int gd = 2;              // g-index of next DMA chunk (S+2)
  bool zpA = false;        // pad flag for the chunk packed this iter (S+1)

#pragma unroll 2
  for (int S = 0; S < NSTEPS; ++S) {
    __builtin_amdgcn_sched_barrier(0);
    asm volatile("s_waitcnt lgkmcnt(0)" ::: "memory");  // Bp writes committed
    __builtin_amdgcn_s_barrier();                       // NO vmcnt drain
    __builtin_amdgcn_sched_barrier(0);

    // seed A recurrence at i-boundaries (S = 0,19,38,57) BEFORE DMA issue,
    // so the compiler's wait for x doesn't drain the DMA queue.
    if (gs == 0) {
      const int i = ks * IPW + il;
#pragma unroll
      for (int tI = 0; tI < 4; ++tI) {
        const float xr = x[(size_t)(mbase + tI * 16 + fr) * IDIM + i] * INV2PI;
        cossin(xr, r1c[tI], r1s[tI]);                   // delta-k = 1
        cossin(16.0f * xr, r16c[tI], r16s[tI]);         // delta-g = 16 per chunk
        cossin((float)(fq * 4 + 1) * xr, sc_[tI], ss_[tI]);
      }
    }

    // issue DMA for chunk S+2 into Bf[S&1] (parity const under unroll-2)
    bool zpB = false;
    if (S < NSTEPS - 2) {
      if (gd == 0) fo += GRIDSZ - (CHUNKS - 1) * 16;   // row wrap: +12
      else fo += 16;
      zpB = (gd == CHUNKS - 1) & (fq == 3);            // pad quads of S+2
      const int sub = zpB ? 4 : 0;                     // shift in-bounds
      dma16(fc + fo - sub, &Bf[S & 1][sa]);
      dma16(b1 + fo - sub, &Bf[S & 1][1024 + sa]);
      gd++; if (gd == CHUNKS) gd = 0;
    }

    // B fragments for this chunk (all 4 waves read all 4 frags)
    const unsigned int* buf = &Bp[S & 1][0];
    short8 bV0 = __builtin_bit_cast(short8, *(const u32x4*)(buf + lane * 4));
    short8 bV1 = __builtin_bit_cast(short8, *(const u32x4*)(buf + 256 + lane * 4));
    short8 bV2 = __builtin_bit_cast(short8, *(const u32x4*)(buf + 512 + lane * 4));
    short8 bV3 = __builtin_bit_cast(short8, *(const u32x4*)(buf + 768 + lane * 4));

    // A frags on the fly + MFMA (pad k-slots hit zeroed B dwords)
#pragma unroll
    for (int tI = 0; tI < 4; ++tI) {
      float c = sc_[tI], s = ss_[tI];
      unsigned a0 = pk(c, s);
      rot(c, s, r1c[tI], r1s[tI]); unsigned a1 = pk(c, s);
      rot(c, s, r1c[tI], r1s[tI]); unsigned a2 = pk(c, s);
      rot(c, s, r1c[tI], r1s[tI]); unsigned a3 = pk(c, s);
      rot(sc_[tI], ss_[tI], r16c[tI], r16s[tI]);   // advance state by delta-g=16
      short8 aV = __builtin_bit_cast(short8, (u32x4){a0, a1, a2, a3});
      acc[tI][0] = __builtin_amdgcn_mfma_f32_16x16x32_bf16(aV, bV0, acc[tI][0], 0, 0, 0);
      acc[tI][1] = __builtin_amdgcn_mfma_f32_16x16x32_bf16(aV, bV1, acc[tI][1], 0, 0, 0);
      acc[tI][2] = __builtin_amdgcn_mfma_f32_16x16x32_bf16(aV, bV2, acc[tI][2], 0, 0, 0);
      acc[tI][3] = __builtin_amdgcn_mfma_f32_16x16x32_bf16(aV, bV3, acc[tI][3], 0, 0, 0);
    }

    // pack chunk S+1: counted vmcnt leaves chunk S+2's DMAs in flight
    if (S < NSTEPS - 1) {
      if (S < NSTEPS - 2) {
        asm volatile("s_waitcnt vmcnt(2)" ::: "memory");
      } else {
        asm volatile("s_waitcnt vmcnt(0)" ::: "memory");  // last chunk: drain
      }
      const f32x4 La = *(const f32x4*)&Bf[(S + 1) & 1][sa];
      const f32x4 Lb = *(const f32x4*)&Bf[(S + 1) & 1][1024 + sa];
      u32x4 w = (u32x4){pk(La.x, Lb.x), pk(La.y, Lb.y),
                        pk(La.z, Lb.z), pk(La.w, Lb.w)};
      if (zpA) w = (u32x4){0u, 0u, 0u, 0u};
      *(u32x4*)&Bp[(S + 1) & 1][sa] = w;
    }
    zpA = zpB;
    gs++; if (gs == CHUNKS) { gs = 0; ++il; }
  }

  // epilogue: C/D layout col=lane&15, row=(lane>>4)*4+reg [m89]; K-split fp32 atomics
  const int ob = mbase + fq * 4;
  const int oj = nbase + fr;
#pragma unroll
  for (int tI = 0; tI < 4; ++tI)
#pragma unroll
    for (int tJ = 0; tJ < 4; ++tJ) {
      float* dst = out + (size_t)(ob + tI * 16) * ODIM + (oj + tJ * 16);
#pragma unroll
      for (int rr = 0; rr < 4; ++rr)
        unsafeAtomicAdd(dst + rr * ODIM, acc[tI][tJ][rr]);
    }
}

extern "C" void kernel_launch(void* const* d_in, const int* in_sizes, int n_in,
                              void* d_out, int out_size, void* d_ws, size_t ws_size,
                              hipStream_t stream) {
  const float* x    = (const float*)d_in[0];
  const float* fc   = (const float*)d_in[1];
  const float* bias = (const float*)d_in[2];
  float* out = (float*)d_out;

  init_out<<<dim3(BATCH * ODIM / 256), dim3(256), 0, stream>>>(bias, out);
  fkan_pipe<<<dim3(4 * 4 * KS_), dim3(256), 0, stream>>>(x, fc, out);
}